// Round 7
// baseline (106.209 us; speedup 1.0000x reference)
//
#include <hip/hip_runtime.h>

namespace {
constexpr int CIN = 64, COUT = 64, SS = 1024, KK = 3;
constexpr int STL = 4;            // s per block
constexpr int POS = STL + 2;      // 6 halo positions
constexpr int NCG = 8, CPG = 8;   // 8 c-groups of 8 channels
}

struct F3 { float x, y, z; };     // 12-B weight chunk -> global_load_dwordx3

// Grid 1024 = 256 s-tiles x 4 o-quarters; block 128 thr (2 waves) -> 4 blocks/CU.
// R7 theory: the ~28us plateau is phase LOCKSTEP (serial stage->load->FMA->reduce,
// weight stream idle 60% of the time). Fix: (a) half the weight stream issued
// PRE-barrier (rides the staging drain), other half issued immediately POST-barrier
// so compute(c0..3) overlaps flight(c4..7); (b) 4 independent blocks/CU for
// cross-block phase staggering. Weights still read exactly once (o-partition).
// All array indices compile-time (R3 lesson: runtime index -> scratch).
__global__ __launch_bounds__(128, 2)
void locon1d(const float* __restrict__ in, const float* __restrict__ wt,
             const float* __restrict__ bias, float* __restrict__ out) {
  __shared__ float smem[6144];  // 24 KB: xs 6144 floats; reduce buf 2048 aliases it

  const int tid = threadIdx.x;
  const int sl  = tid & 3;
  const int og  = (tid >> 2) & 3;
  const int cg  = tid >> 4;          // 0..7
  const int bid = blockIdx.x;
  const int oq  = bid >> 8;          // o-quarter 0..3
  // same s-tile's 4 o-quarter blocks differ by +256 -> same XCD (bid%8) -> input L2 hits
  const int st  = ((bid & 7) << 5) + ((bid >> 3) & 31);
  const int s0  = st * STL;
  const int s   = s0 + sl;
  const int o0  = oq * 16 + og * 4;
  const int cb  = cg * CPG;

  // ---- stage input tile to LDS: xs[c][p][b], 64c x 6pos x 16b (24 KB) ----
  #pragma unroll
  for (int i = 0; i < 12; ++i) {
    const int t  = tid + i * 128;      // 0..1535 = 64c * 6p * 4bq
    const int c  = t / 24;
    const int r  = t - c * 24;
    const int bq = r / 6;
    const int p  = r - bq * 6;
    const int sg = s0 - 1 + p;
    const bool v = (unsigned)sg < (unsigned)SS;
    const float* ip = in + ((size_t)(4 * bq) * CIN + c) * SS + sg;
    float4 x4;
    x4.x = v ? ip[0] : 0.f;
    x4.y = v ? ip[(size_t)1 * CIN * SS] : 0.f;
    x4.z = v ? ip[(size_t)2 * CIN * SS] : 0.f;
    x4.w = v ? ip[(size_t)3 * CIN * SS] : 0.f;
    *reinterpret_cast<float4*>(&smem[(c * POS + p) * 16 + 4 * bq]) = x4;
  }

  // ---- weight bases; FIRST HALF (c=0..3) issued pre-barrier: rides the drain ----
  const float* wb0 = wt + (((size_t)(o0 + 0) * CIN + cb) * SS + s) * KK;
  const float* wb1 = wt + (((size_t)(o0 + 1) * CIN + cb) * SS + s) * KK;
  const float* wb2 = wt + (((size_t)(o0 + 2) * CIN + cb) * SS + s) * KK;
  const float* wb3 = wt + (((size_t)(o0 + 3) * CIN + cb) * SS + s) * KK;

  F3 wv[CPG][4];   // 96 VGPRs, compile-time indices only
  #pragma unroll
  for (int c = 0; c < 4; ++c) {
    const size_t co = (size_t)c * SS * KK;
    wv[c][0] = *reinterpret_cast<const F3*>(wb0 + co);
    wv[c][1] = *reinterpret_cast<const F3*>(wb1 + co);
    wv[c][2] = *reinterpret_cast<const F3*>(wb2 + co);
    wv[c][3] = *reinterpret_cast<const F3*>(wb3 + co);
  }

  __syncthreads();   // drains staging AND first-half weights together

  // ---- SECOND HALF (c=4..7) issued before any compute: flight overlaps c0..3 ----
  #pragma unroll
  for (int c = 4; c < CPG; ++c) {
    const size_t co = (size_t)c * SS * KK;
    wv[c][0] = *reinterpret_cast<const F3*>(wb0 + co);
    wv[c][1] = *reinterpret_cast<const F3*>(wb1 + co);
    wv[c][2] = *reinterpret_cast<const F3*>(wb2 + co);
    wv[c][3] = *reinterpret_cast<const F3*>(wb3 + co);
  }

  // ---- compute: 8c x 3k x 16b x 4o FMAs, LDS b128 reads ----
  float acc[4][16];
  #pragma unroll
  for (int oo = 0; oo < 4; ++oo)
    #pragma unroll
    for (int b = 0; b < 16; ++b) acc[oo][b] = 0.f;

  #pragma unroll
  for (int c = 0; c < CPG; ++c) {
    #pragma unroll
    for (int k = 0; k < KK; ++k) {
      const float* base = &smem[((cb + c) * POS + sl + k) * 16];
      #pragma unroll
      for (int g = 0; g < 4; ++g) {
        const float4 x4 = *reinterpret_cast<const float4*>(base + 4 * g);
        #pragma unroll
        for (int oo = 0; oo < 4; ++oo) {
          const float wk = (k == 0) ? wv[c][oo].x
                         : (k == 1) ? wv[c][oo].y
                                    : wv[c][oo].z;
          acc[oo][4 * g + 0] += wk * x4.x;
          acc[oo][4 * g + 1] += wk * x4.y;
          acc[oo][4 * g + 2] += wk * x4.z;
          acc[oo][4 * g + 3] += wk * x4.w;
        }
      }
    }
  }

  // ---- in-block reduction over cg (8 partials), 4 rounds over oo ----
  // buffer: smem[cg*256 + (b*4+og)*4 + sl]  (2048 floats; aliases dead xs)
  #pragma unroll
  for (int oo = 0; oo < 4; ++oo) {
    __syncthreads();                    // round 0 also guards xs alias
    #pragma unroll
    for (int b = 0; b < 16; ++b)
      smem[cg * 256 + (b * 4 + og) * 4 + sl] = acc[oo][b];
    __syncthreads();
    #pragma unroll
    for (int i = 0; i < 2; ++i) {
      const int item = tid + i * 128;   // 0..255 = (b 0..15, og2 0..3, sl2 0..3)
      float sum = 0.f;
      #pragma unroll
      for (int g = 0; g < NCG; ++g) sum += smem[g * 256 + item];
      const int b   = item >> 4;
      const int rem = item & 15;
      const int o   = oq * 16 + (rem >> 2) * 4 + oo;
      const int s2  = s0 + (rem & 3);
      out[((size_t)b * COUT + o) * SS + s2] = sum + bias[o * SS + s2];
    }
  }
}

extern "C" void kernel_launch(void* const* d_in, const int* in_sizes, int n_in,
                              void* d_out, int out_size, void* d_ws, size_t ws_size,
                              hipStream_t stream) {
  const float* in = (const float*)d_in[0];
  const float* wt = (const float*)d_in[1];
  const float* bs = (const float*)d_in[2];
  float* out = (float*)d_out;
  // 256 s-tiles x 4 o-quarters = 1024 blocks x 2 waves -> 4 blocks/CU, 8 waves/CU
  hipLaunchKernelGGL(locon1d, dim3(1024), dim3(128), 0, stream, in, wt, bs, out);
}

// Round 8
// 106.078 us; speedup vs baseline: 1.0012x; 1.0012x over previous
//
#include <hip/hip_runtime.h>

namespace {
constexpr int CIN = 64, COUT = 64, SS = 1024, KK = 3;
constexpr int STL = 4;            // s per block
constexpr int POS = STL + 2;      // 6 halo positions
constexpr int NCG = 8, CPG = 8;   // 8 c-groups of 8 channels
}

struct F3 { float x, y, z; };     // 12-B weight chunk -> global_load_dwordx3

// R8: occupancy experiment. 2 o's/thread (was 4) -> ~115 VGPR -> 4 waves/SIMD.
// Grid 1024 = 256 s-tiles x 4 o-quarters; block 256 thr (4 waves) x 4 blocks/CU
// = 16 waves/CU (every prior round was 8). Theory: weight stream is
// outstanding-lines starved; 2x waves -> 2x lines in flight -> stream rate up.
// Weights still read exactly once (o-partition). All indices compile-time.
__global__ __launch_bounds__(256, 4)
void locon1d(const float* __restrict__ in, const float* __restrict__ wt,
             const float* __restrict__ bias, float* __restrict__ out) {
  __shared__ float smem[6144];  // 24 KB: xs 6144 floats; reduce buf 4096 aliases it

  const int tid = threadIdx.x;
  const int sl  = tid & 3;
  const int og  = (tid >> 2) & 7;    // 8 o-pairs
  const int cg  = tid >> 5;          // 8 c-groups
  const int bid = blockIdx.x;
  const int oq  = bid >> 8;          // o-quarter 0..3 (bid%8 invariant -> same XCD)
  const int st  = ((bid & 7) << 5) + ((bid >> 3) & 31);
  const int s0  = st * STL;
  const int s   = s0 + sl;
  const int o0  = oq * 16 + og * 2;  // this thread's o-pair
  const int cb  = cg * CPG;

  // ---- stage input tile to LDS: xs[c][p][b], 64c x 6pos x 16b (24 KB) ----
  #pragma unroll
  for (int i = 0; i < 6; ++i) {
    const int t  = tid + i * 256;      // 0..1535 = 64c * 6p * 4bq
    const int c  = t / 24;
    const int r  = t - c * 24;
    const int bq = r / 6;
    const int p  = r - bq * 6;
    const int sg = s0 - 1 + p;
    const bool v = (unsigned)sg < (unsigned)SS;
    const float* ip = in + ((size_t)(4 * bq) * CIN + c) * SS + sg;
    float4 x4;
    x4.x = v ? ip[0] : 0.f;
    x4.y = v ? ip[(size_t)1 * CIN * SS] : 0.f;
    x4.z = v ? ip[(size_t)2 * CIN * SS] : 0.f;
    x4.w = v ? ip[(size_t)3 * CIN * SS] : 0.f;
    *reinterpret_cast<float4*>(&smem[(c * POS + p) * 16 + 4 * bq]) = x4;
  }
  __syncthreads();

  // ---- weight preload: 16 dwordx3 loads (8c x 2o), c-major == consumption order ----
  F3 wv[CPG][2];   // 48 VGPRs, compile-time indices only
  {
    const float* wb0 = wt + (((size_t)(o0 + 0) * CIN + cb) * SS + s) * KK;
    const float* wb1 = wt + (((size_t)(o0 + 1) * CIN + cb) * SS + s) * KK;
    #pragma unroll
    for (int c = 0; c < CPG; ++c) {
      const size_t co = (size_t)c * SS * KK;
      wv[c][0] = *reinterpret_cast<const F3*>(wb0 + co);
      wv[c][1] = *reinterpret_cast<const F3*>(wb1 + co);
    }
  }

  // ---- compute: 8c x 3k x 16b x 2o FMAs, LDS b128 reads ----
  float acc[2][16];
  #pragma unroll
  for (int oo = 0; oo < 2; ++oo)
    #pragma unroll
    for (int b = 0; b < 16; ++b) acc[oo][b] = 0.f;

  #pragma unroll
  for (int c = 0; c < CPG; ++c) {
    #pragma unroll
    for (int k = 0; k < KK; ++k) {
      const float* base = &smem[((cb + c) * POS + sl + k) * 16];
      #pragma unroll
      for (int g = 0; g < 4; ++g) {
        const float4 x4 = *reinterpret_cast<const float4*>(base + 4 * g);
        #pragma unroll
        for (int oo = 0; oo < 2; ++oo) {
          const float wk = (k == 0) ? wv[c][oo].x
                         : (k == 1) ? wv[c][oo].y
                                    : wv[c][oo].z;
          acc[oo][4 * g + 0] += wk * x4.x;
          acc[oo][4 * g + 1] += wk * x4.y;
          acc[oo][4 * g + 2] += wk * x4.z;
          acc[oo][4 * g + 3] += wk * x4.w;
        }
      }
    }
  }

  // ---- in-block reduction over cg (8 partials), 2 rounds over oo ----
  // buffer: smem[cg*512 + (b*8+og)*4 + sl]  (4096 floats; aliases dead xs)
  #pragma unroll
  for (int oo = 0; oo < 2; ++oo) {
    __syncthreads();                    // round 0 also guards xs alias
    #pragma unroll
    for (int b = 0; b < 16; ++b)
      smem[cg * 512 + (b * 8 + og) * 4 + sl] = acc[oo][b];
    __syncthreads();
    #pragma unroll
    for (int i = 0; i < 2; ++i) {
      const int item = tid + i * 256;   // 0..511 = (b 0..15, og2 0..7, sl2 0..3)
      float sum = 0.f;
      #pragma unroll
      for (int g = 0; g < NCG; ++g) sum += smem[g * 512 + item];
      const int b   = item >> 5;
      const int rem = item & 31;
      const int o   = oq * 16 + (rem >> 2) * 2 + oo;
      const int s2  = s0 + (rem & 3);
      out[((size_t)b * COUT + o) * SS + s2] = sum + bias[o * SS + s2];
    }
  }
}

extern "C" void kernel_launch(void* const* d_in, const int* in_sizes, int n_in,
                              void* d_out, int out_size, void* d_ws, size_t ws_size,
                              hipStream_t stream) {
  const float* in = (const float*)d_in[0];
  const float* wt = (const float*)d_in[1];
  const float* bs = (const float*)d_in[2];
  float* out = (float*)d_out;
  // 256 s-tiles x 4 o-quarters = 1024 blocks x 4 waves -> 4 blocks/CU, 16 waves/CU
  hipLaunchKernelGGL(locon1d, dim3(1024), dim3(256), 0, stream, in, wt, bs, out);
}